// Round 1
// baseline (325.855 us; speedup 1.0000x reference)
//
#include <hip/hip_runtime.h>
#include <hip/hip_bf16.h>
#include <cmath>

#define DIM 512
#define HID 256
#define BM 64

typedef __attribute__((ext_vector_type(8))) short short8;
typedef __attribute__((ext_vector_type(4))) float f32x4;

__device__ __forceinline__ unsigned short f2bf(float f) {
  union { float f; unsigned u; } v; v.f = f;
  unsigned u = v.u;
  return (unsigned short)((u + 0x7FFFu + ((u >> 16) & 1u)) >> 16);
}

// Pre-swizzle W1 (fp32 [512,256] row-major) into bf16 fragment order:
// w1s[((k>>3)*HID + c)*8 + (k&7)] so that each K-step's B tile is one
// contiguous 16 KB block and each lane's MFMA B-fragment is a contiguous
// 16 B ds_read_b128.
__global__ void w1_swz_kernel(const float* __restrict__ W1,
                              unsigned short* __restrict__ w1s) {
  int tid = blockIdx.x * blockDim.x + threadIdx.x;
  if (tid >= DIM * HID) return;
  int k = tid / HID;
  int c = tid - k * HID;
  w1s[(((k >> 3) * HID) + c) * 8 + (k & 7)] = f2bf(W1[tid]);
}

__global__ __launch_bounds__(256) void fa_main_kernel(
    const float* __restrict__ z1, const float* __restrict__ z2,
    const unsigned short* __restrict__ w1s,
    const float* __restrict__ b1, const float* __restrict__ W2,
    const float* __restrict__ b2, float* __restrict__ out, int n) {
  // LDS: B tile [ko=4][c=256][ki=8] bf16 (16 KB), A tile [ko=4][row=64][ki=8]
  // bf16 (4 KB), per-row logits for both sources (512 B).
  __shared__ unsigned short Bs[4 * HID * 8];
  __shared__ unsigned short As[4 * BM * 8];
  __shared__ float xs[2][BM];

  const int t = threadIdx.x;
  const int w = t >> 6;        // wave id: 16-row slab
  const int l = t & 63;
  const int l15 = l & 15;
  const int l16 = l >> 4;
  const int row0 = blockIdx.x * BM;
  const int V = min(BM, n - row0);
  const int arow = t & 63;     // staging: row
  const int ako = t >> 6;      // staging: k-group

  for (int s = 0; s < 2; ++s) {
    const float* zz = s ? z2 : z1;
    f32x4 acc[16];
#pragma unroll
    for (int f = 0; f < 16; ++f) acc[f] = (f32x4){0.f, 0.f, 0.f, 0.f};

    for (int ks = 0; ks < 16; ++ks) {
      __syncthreads();
      // Stage B: contiguous 16 KB copy, 64 B per thread, fully linear.
      {
        const f32x4* src = (const f32x4*)(w1s + ks * (4 * HID * 8));
        f32x4* dst = (f32x4*)Bs;
#pragma unroll
        for (int q = 0; q < 4; ++q) dst[q * 256 + t] = src[q * 256 + t];
      }
      // Stage A: each thread converts 8 fp32 z-values -> bf16x8, linear store.
      {
        short8 av;
        if (arow < V) {
          const float* g =
              zz + (size_t)(row0 + arow) * DIM + (ks << 5) + (ako << 3);
          const f32x4 p0 = *(const f32x4*)g;
          const f32x4 p1 = *(const f32x4*)(g + 4);
          av[0] = (short)f2bf(p0[0]);
          av[1] = (short)f2bf(p0[1]);
          av[2] = (short)f2bf(p0[2]);
          av[3] = (short)f2bf(p0[3]);
          av[4] = (short)f2bf(p1[0]);
          av[5] = (short)f2bf(p1[1]);
          av[6] = (short)f2bf(p1[2]);
          av[7] = (short)f2bf(p1[3]);
        } else {
          av = (short8){0, 0, 0, 0, 0, 0, 0, 0};
        }
        ((short8*)As)[t] = av;  // index == ako*64 + arow == t
      }
      __syncthreads();

      const short8 a = ((const short8*)As)[l16 * 64 + (w << 4) + l15];
#pragma unroll
      for (int f = 0; f < 16; ++f) {
        const short8 b = ((const short8*)Bs)[l16 * 256 + (f << 4) + l15];
        acc[f] = __builtin_amdgcn_mfma_f32_16x16x32_bf16(a, b, acc[f], 0, 0, 0);
      }
    }

    // x[row] = sum_c relu(H[row][c] + b1[c]) * W2[c] + b2, fully fp32.
    // C/D layout: col = l&15, row = (l>>4)*4 + r.
    float part[4];
    part[0] = part[1] = part[2] = part[3] = 0.f;
#pragma unroll
    for (int f = 0; f < 16; ++f) {
      const int c = (f << 4) + l15;
      const float w2 = W2[c];
      const float bb = b1[c];
#pragma unroll
      for (int r = 0; r < 4; ++r) {
        const float h = acc[f][r] + bb;
        part[r] += (h > 0.f) ? h * w2 : 0.f;
      }
    }
#pragma unroll
    for (int r = 0; r < 4; ++r) {
      part[r] += __shfl_xor(part[r], 1, 16);
      part[r] += __shfl_xor(part[r], 2, 16);
      part[r] += __shfl_xor(part[r], 4, 16);
      part[r] += __shfl_xor(part[r], 8, 16);
    }
    if (l15 == 0) {
      const float bias2 = b2[0];
#pragma unroll
      for (int r = 0; r < 4; ++r)
        xs[s][(w << 4) + (l16 << 2) + r] = part[r] + bias2;
    }
  }
  __syncthreads();

  // Epilogue: out = sx*z1 + sy*z2, streaming fp32 re-read of z (L2-assisted).
  const size_t base = (size_t)row0 * DIM;
  for (int i = 0; i < 32; ++i) {
    const int idx = i * 256 + t;  // float4 index within the 64x512 tile
    const int row = idx >> 7;
    const int c4 = idx & 127;
    if (row < V) {
      const float x = xs[0][row];
      const float y = xs[1][row];
      const float d = y - x;
      const float sx = 1.f / (1.f + expf(d));
      const float sy = 1.f / (1.f + expf(-d));
      const size_t off = base + (size_t)row * DIM + (size_t)(c4 << 2);
      const f32x4 a4 = *(const f32x4*)(z1 + off);
      const f32x4 b4 = *(const f32x4*)(z2 + off);
      f32x4 o;
      o[0] = sx * a4[0] + sy * b4[0];
      o[1] = sx * a4[1] + sy * b4[1];
      o[2] = sx * a4[2] + sy * b4[2];
      o[3] = sx * a4[3] + sy * b4[3];
      *(f32x4*)(out + off) = o;
    }
  }
}

extern "C" void kernel_launch(void* const* d_in, const int* in_sizes, int n_in,
                              void* d_out, int out_size, void* d_ws,
                              size_t ws_size, hipStream_t stream) {
  const float* z1 = (const float*)d_in[0];
  const float* z2 = (const float*)d_in[1];
  const float* W1 = (const float*)d_in[2];
  const float* b1 = (const float*)d_in[3];
  const float* W2 = (const float*)d_in[4];
  const float* b2 = (const float*)d_in[5];
  float* out = (float*)d_out;
  const int n = in_sizes[0] / DIM;
  unsigned short* w1s = (unsigned short*)d_ws;  // 512*256*2 = 256 KB

  hipLaunchKernelGGL(w1_swz_kernel, dim3((DIM * HID + 255) / 256), dim3(256),
                     0, stream, W1, w1s);
  const int nwg = (n + BM - 1) / BM;
  hipLaunchKernelGGL(fa_main_kernel, dim3(nwg), dim3(256), 0, stream, z1, z2,
                     w1s, b1, W2, b2, out, n);
}

// Round 2
// 307.140 us; speedup vs baseline: 1.0609x; 1.0609x over previous
//
#include <hip/hip_runtime.h>
#include <hip/hip_bf16.h>
#include <cmath>

#define DIM 512
#define HID 256

typedef __attribute__((ext_vector_type(8))) short short8;
typedef __attribute__((ext_vector_type(4))) float f32x4;

__device__ __forceinline__ unsigned short f2bf(float f) {
  union { float f; unsigned u; } v; v.f = f;
  unsigned u = v.u;
  return (unsigned short)((u + 0x7FFFu + ((u >> 16) & 1u)) >> 16);
}

// Pre-swizzle W1 (fp32 [512,256] row-major) into bf16 fragment order:
// w1s[((k>>3)*HID + c)*8 + (k&7)]. Lane l's B-fragment for k-group kg and
// column c is then the contiguous 16 B at short8-index kg*HID + c.
__global__ void w1_swz_kernel(const float* __restrict__ W1,
                              unsigned short* __restrict__ w1s) {
  int tid = blockIdx.x * blockDim.x + threadIdx.x;
  if (tid >= DIM * HID) return;
  int k = tid / HID;
  int c = tid - k * HID;
  w1s[(((k >> 3) * HID) + c) * 8 + (k & 7)] = f2bf(W1[tid]);
}

__device__ __forceinline__ short8 cvt8(const f32x4 p0, const f32x4 p1) {
  short8 r;
  r[0] = (short)f2bf(p0[0]); r[1] = (short)f2bf(p0[1]);
  r[2] = (short)f2bf(p0[2]); r[3] = (short)f2bf(p0[3]);
  r[4] = (short)f2bf(p1[0]); r[5] = (short)f2bf(p1[1]);
  r[6] = (short)f2bf(p1[2]); r[7] = (short)f2bf(p1[3]);
  return r;
}

// One wave == 16 rows, fully independent. No LDS, no barriers.
__global__ __launch_bounds__(256, 2) void fa_main_kernel(
    const float* __restrict__ z1, const float* __restrict__ z2,
    const unsigned short* __restrict__ w1s,
    const float* __restrict__ b1, const float* __restrict__ W2,
    const float* __restrict__ b2, float* __restrict__ out, int n) {
  const int t = threadIdx.x;
  const int wid = blockIdx.x * 4 + (t >> 6);
  const int l = t & 63;
  const int l15 = l & 15;
  const int l16 = l >> 4;
  const int row0 = wid * 16;
  if (row0 >= n) return;

  const int myrow = row0 + l15;
  const bool rok = myrow < n;
  // A-fragment stream: 8 consecutive fp32 per lane, already in MFMA order.
  const float* a1p = z1 + (size_t)myrow * DIM + (l16 << 3);
  const float* a2p = z2 + (size_t)myrow * DIM + (l16 << 3);
  const short8* bbase = (const short8*)w1s;

  f32x4 acc1[16], acc2[16];
#pragma unroll
  for (int f = 0; f < 16; ++f) {
    acc1[f] = (f32x4){0.f, 0.f, 0.f, 0.f};
    acc2[f] = (f32x4){0.f, 0.f, 0.f, 0.f};
  }

  const f32x4 zero4 = (f32x4){0.f, 0.f, 0.f, 0.f};
  // Software-pipelined A loads (issue next step's HBM loads before MFMAs).
  f32x4 a1v0 = rok ? *(const f32x4*)(a1p) : zero4;
  f32x4 a1v1 = rok ? *(const f32x4*)(a1p + 4) : zero4;
  f32x4 a2v0 = rok ? *(const f32x4*)(a2p) : zero4;
  f32x4 a2v1 = rok ? *(const f32x4*)(a2p + 4) : zero4;

  for (int ks = 0; ks < 16; ++ks) {
    const short8 a1f = cvt8(a1v0, a1v1);
    const short8 a2f = cvt8(a2v0, a2v1);
    if (ks < 15) {
      const float* p1 = a1p + ((ks + 1) << 5);
      const float* p2 = a2p + ((ks + 1) << 5);
      a1v0 = rok ? *(const f32x4*)(p1) : zero4;
      a1v1 = rok ? *(const f32x4*)(p1 + 4) : zero4;
      a2v0 = rok ? *(const f32x4*)(p2) : zero4;
      a2v1 = rok ? *(const f32x4*)(p2 + 4) : zero4;
    }
    const short8* bp = bbase + (((ks << 2) + l16) * HID) + l15;
#pragma unroll
    for (int f = 0; f < 16; ++f) {
      const short8 bf = bp[f << 4];
      acc1[f] = __builtin_amdgcn_mfma_f32_16x16x32_bf16(a1f, bf, acc1[f], 0, 0, 0);
      acc2[f] = __builtin_amdgcn_mfma_f32_16x16x32_bf16(a2f, bf, acc2[f], 0, 0, 0);
    }
  }

  // Per-row logits: x = sum_c relu(H+b1)*W2 + b2.  C/D: col=l15, row=l16*4+r.
  float p1s[4] = {0.f, 0.f, 0.f, 0.f};
  float p2s[4] = {0.f, 0.f, 0.f, 0.f};
#pragma unroll
  for (int f = 0; f < 16; ++f) {
    const int c = (f << 4) + l15;
    const float w2v = W2[c];
    const float b1v = b1[c];
#pragma unroll
    for (int r = 0; r < 4; ++r) {
      const float h1 = acc1[f][r] + b1v;
      p1s[r] += (h1 > 0.f) ? h1 * w2v : 0.f;
      const float h2 = acc2[f][r] + b1v;
      p2s[r] += (h2 > 0.f) ? h2 * w2v : 0.f;
    }
  }
#pragma unroll
  for (int r = 0; r < 4; ++r) {
#pragma unroll
    for (int m = 1; m < 16; m <<= 1) {
      p1s[r] += __shfl_xor(p1s[r], m, 16);
      p2s[r] += __shfl_xor(p2s[r], m, 16);
    }
  }
  // scores: sigmoid(x - y) pairing; rows l16*4+r live in lane group l16.
  float sx[4], sy[4];
#pragma unroll
  for (int r = 0; r < 4; ++r) {
    const float d = p2s[r] - p1s[r];  // y - x (b2 cancels)
    sx[r] = 1.f / (1.f + expf(d));
    sy[r] = 1.f - sx[r];
  }

  // Epilogue: out = sx*z1 + sy*z2 for the 16 rows (re-reads are L2/L3 hits).
#pragma unroll
  for (int rr = 0; rr < 16; ++rr) {
    const float sxv = __shfl(sx[rr & 3], (rr >> 2) << 4, 64);
    const float syv = __shfl(sy[rr & 3], (rr >> 2) << 4, 64);
    const int row = row0 + rr;
    if (row < n) {
      const size_t off = (size_t)row * DIM;
#pragma unroll
      for (int it = 0; it < 2; ++it) {
        const size_t c = off + ((it << 6) + l) * 4;
        const f32x4 a4 = *(const f32x4*)(z1 + c);
        const f32x4 b4 = *(const f32x4*)(z2 + c);
        f32x4 o;
        o[0] = sxv * a4[0] + syv * b4[0];
        o[1] = sxv * a4[1] + syv * b4[1];
        o[2] = sxv * a4[2] + syv * b4[2];
        o[3] = sxv * a4[3] + syv * b4[3];
        *(f32x4*)(out + c) = o;
      }
    }
  }
}

extern "C" void kernel_launch(void* const* d_in, const int* in_sizes, int n_in,
                              void* d_out, int out_size, void* d_ws,
                              size_t ws_size, hipStream_t stream) {
  const float* z1 = (const float*)d_in[0];
  const float* z2 = (const float*)d_in[1];
  const float* W1 = (const float*)d_in[2];
  const float* b1 = (const float*)d_in[3];
  const float* W2 = (const float*)d_in[4];
  const float* b2 = (const float*)d_in[5];
  float* out = (float*)d_out;
  const int n = in_sizes[0] / DIM;
  unsigned short* w1s = (unsigned short*)d_ws;  // 512*256*2 = 256 KB

  hipLaunchKernelGGL(w1_swz_kernel, dim3((DIM * HID + 255) / 256), dim3(256),
                     0, stream, W1, w1s);
  const int nwaves = (n + 15) / 16;
  const int nwg = (nwaves + 3) / 4;
  hipLaunchKernelGGL(fa_main_kernel, dim3(nwg), dim3(256), 0, stream, z1, z2,
                     w1s, b1, W2, b2, out, n);
}

// Round 3
// 212.969 us; speedup vs baseline: 1.5301x; 1.4422x over previous
//
#include <hip/hip_runtime.h>
#include <hip/hip_bf16.h>
#include <cmath>

#define DIM 512
#define HID 256
#define NW 12        // waves per block
#define TILES 6      // 16-row tiles per block (per source)
#define ROWS_PB 96   // rows per block
#define NCHUNK 8     // K chunks of 64
#define CHUNK_BYTES 32768  // 64k * 256c * 2B
#define ROUNDS 32          // CHUNK_BYTES / 1024B-per-wave-call

typedef __attribute__((ext_vector_type(8))) short short8;
typedef __attribute__((ext_vector_type(4))) float f32x4;

__device__ __forceinline__ unsigned short f2bf(float f) {
  union { float f; unsigned u; } v; v.f = f;
  unsigned u = v.u;
  return (unsigned short)((u + 0x7FFFu + ((u >> 16) & 1u)) >> 16);
}

// Pre-swizzle W1 (fp32 [512,256] row-major) into bf16 MFMA fragment order:
// w1s[((k>>3)*HID + c)*8 + (k&7)]. K-chunk c (64 k's) is then the contiguous
// 32 KB at byte offset c*32768 — a linear global_load_lds copy.
__global__ void w1_swz_kernel(const float* __restrict__ W1,
                              unsigned short* __restrict__ w1s) {
  int tid = blockIdx.x * blockDim.x + threadIdx.x;
  if (tid >= DIM * HID) return;
  int k = tid / HID;
  int c = tid - k * HID;
  w1s[(((k >> 3) * HID) + c) * 8 + (k & 7)] = f2bf(W1[tid]);
}

__device__ __forceinline__ short8 cvt8(const f32x4 p0, const f32x4 p1) {
  short8 r;
  r[0] = (short)f2bf(p0[0]); r[1] = (short)f2bf(p0[1]);
  r[2] = (short)f2bf(p0[2]); r[3] = (short)f2bf(p0[3]);
  r[4] = (short)f2bf(p1[0]); r[5] = (short)f2bf(p1[1]);
  r[6] = (short)f2bf(p1[2]); r[7] = (short)f2bf(p1[3]);
  return r;
}

// 12 waves: waves 0-5 score z1 rows, waves 6-11 score z2 rows (same 96 rows).
// B (W1 bf16) staged in LDS in 32 KB double-buffered K-chunks via
// global_load_lds; one barrier per chunk is the only drain point.
__global__ __launch_bounds__(768, 3) void fa_main_kernel(
    const float* __restrict__ z1, const float* __restrict__ z2,
    const unsigned short* __restrict__ w1s,
    const float* __restrict__ b1, const float* __restrict__ W2,
    const float* __restrict__ b2, float* __restrict__ out, int n) {
  __shared__ unsigned short Bs[2][CHUNK_BYTES / 2];

  const int t = threadIdx.x;
  const int w = t >> 6;
  const int l = t & 63;
  const int l15 = l & 15, l16 = l >> 4;
  const int src = (w >= TILES) ? 1 : 0;
  const int tile = src ? (w - TILES) : w;
  const int row0 = blockIdx.x * ROWS_PB;
  const int myrow = row0 + tile * 16 + l15;
  const bool rok = myrow < n;
  const float* zz = src ? z2 : z1;
  const float* ap = zz + (size_t)myrow * DIM + (l16 << 3);
  const f32x4 zf4 = (f32x4){0.f, 0.f, 0.f, 0.f};

  // Stage chunk 0 (async) + prefetch A for chunk 0.
  {
    const char* gsrc = (const char*)w1s + l * 16;
    for (int r = w; r < ROUNDS; r += NW)
      __builtin_amdgcn_global_load_lds(
          (const __attribute__((address_space(1))) void*)(gsrc + r * 1024),
          (__attribute__((address_space(3))) void*)((char*)&Bs[0][0] + r * 1024),
          16, 0, 0);
  }
  f32x4 pa[4];
#pragma unroll
  for (int q = 0; q < 4; ++q)
    pa[q] = rok ? *(const f32x4*)(ap + ((q >> 1) << 5) + ((q & 1) << 2)) : zf4;

  f32x4 acc[16];
#pragma unroll
  for (int f = 0; f < 16; ++f) acc[f] = zf4;

  __syncthreads();  // drains chunk-0 stage + A prefetch

#pragma unroll 2
  for (int c = 0; c < NCHUNK; ++c) {
    const int cur = c & 1;
    // Issue next chunk's B-stage and A-prefetch BEFORE this chunk's compute.
    if (c + 1 < NCHUNK) {
      const char* gsrc = (const char*)w1s + (c + 1) * CHUNK_BYTES + l * 16;
      for (int r = w; r < ROUNDS; r += NW)
        __builtin_amdgcn_global_load_lds(
            (const __attribute__((address_space(1))) void*)(gsrc + r * 1024),
            (__attribute__((address_space(3))) void*)((char*)&Bs[cur ^ 1][0] +
                                                      r * 1024),
            16, 0, 0);
    }
    f32x4 na[4];
    if (c + 1 < NCHUNK) {
      const float* apn = ap + ((c + 1) << 6);
#pragma unroll
      for (int q = 0; q < 4; ++q)
        na[q] = rok ? *(const f32x4*)(apn + ((q >> 1) << 5) + ((q & 1) << 2))
                    : zf4;
    }
    // Compute chunk c: 2 sub-steps of K=32, 16 col-fragments each.
#pragma unroll
    for (int s = 0; s < 2; ++s) {
      const short8 af = cvt8(pa[(s << 1)], pa[(s << 1) + 1]);
      const short8* bp =
          (const short8*)&Bs[cur][0] + (((s << 2) + l16) << 8) + l15;
#pragma unroll
      for (int f = 0; f < 16; ++f) {
        const short8 bf = bp[f << 4];
        acc[f] =
            __builtin_amdgcn_mfma_f32_16x16x32_bf16(af, bf, acc[f], 0, 0, 0);
      }
    }
    if (c + 1 < NCHUNK) {
#pragma unroll
      for (int q = 0; q < 4; ++q) pa[q] = na[q];
    }
    __syncthreads();  // vmcnt(0)+barrier: next buffer staged, this one free
  }

  // Per-row logit: x = sum_c relu(H+b1)*W2 (+b2, cancels in the pair diff).
  // C/D layout: hidden col = l15 + 16f, row-in-tile = l16*4 + r.
  float part[4] = {0.f, 0.f, 0.f, 0.f};
#pragma unroll
  for (int f = 0; f < 16; ++f) {
    const int cc = (f << 4) + l15;
    const float w2v = W2[cc];
    const float b1v = b1[cc];
#pragma unroll
    for (int r = 0; r < 4; ++r) {
      const float h = acc[f][r] + b1v;
      part[r] += (h > 0.f) ? h * w2v : 0.f;
    }
  }
#pragma unroll
  for (int r = 0; r < 4; ++r) {
#pragma unroll
    for (int m = 1; m < 16; m <<= 1) part[r] += __shfl_xor(part[r], m, 16);
  }
  // Exchange logits via LDS (reuse B buffer — all B reads are done).
  float* xs = (float*)&Bs[0][0];  // xs[src][96]
  if (l15 == 0) {
#pragma unroll
    for (int r = 0; r < 4; ++r)
      xs[src * ROWS_PB + tile * 16 + (l16 << 2) + r] = part[r];
  }
  __syncthreads();

  // Epilogue: wave pair (tile, src) covers its 16 rows; this wave does the
  // 256-col half [src*256, src*256+256). Fully coalesced 1 KB/instr.
#pragma unroll 1
  for (int r = 0; r < 16; ++r) {
    const int rl = tile * 16 + r;
    const int grow = row0 + rl;
    if (grow < n) {
      const float d = xs[ROWS_PB + rl] - xs[rl];  // y - x
      const float sx = 1.f / (1.f + __expf(d));
      const float sy = 1.f - sx;
      const size_t off = (size_t)grow * DIM + (src << 8) + (l << 2);
      const f32x4 a4 = *(const f32x4*)(z1 + off);
      const f32x4 b4 = *(const f32x4*)(z2 + off);
      f32x4 o;
      o[0] = sx * a4[0] + sy * b4[0];
      o[1] = sx * a4[1] + sy * b4[1];
      o[2] = sx * a4[2] + sy * b4[2];
      o[3] = sx * a4[3] + sy * b4[3];
      *(f32x4*)(out + off) = o;
    }
  }
}

extern "C" void kernel_launch(void* const* d_in, const int* in_sizes, int n_in,
                              void* d_out, int out_size, void* d_ws,
                              size_t ws_size, hipStream_t stream) {
  const float* z1 = (const float*)d_in[0];
  const float* z2 = (const float*)d_in[1];
  const float* W1 = (const float*)d_in[2];
  const float* b1 = (const float*)d_in[3];
  const float* W2 = (const float*)d_in[4];
  const float* b2 = (const float*)d_in[5];
  float* out = (float*)d_out;
  const int n = in_sizes[0] / DIM;
  unsigned short* w1s = (unsigned short*)d_ws;  // 512*256*2 = 256 KB

  hipLaunchKernelGGL(w1_swz_kernel, dim3((DIM * HID + 255) / 256), dim3(256),
                     0, stream, W1, w1s);
  const int nwg = (n + ROWS_PB - 1) / ROWS_PB;
  hipLaunchKernelGGL(fa_main_kernel, dim3(nwg), dim3(768), 0, stream, z1, z2,
                     w1s, b1, W2, b2, out, n);
}

// Round 4
// 211.798 us; speedup vs baseline: 1.5385x; 1.0055x over previous
//
#include <hip/hip_runtime.h>
#include <hip/hip_bf16.h>
#include <cmath>

#define DIM 512
#define HID 256
#define ROWS_PB 32       // rows per block
#define NCHUNK 16        // K chunks of 32
#define CB 16384         // chunk bytes: 32k * 256c * 2B

typedef __attribute__((ext_vector_type(8))) short short8;
typedef __attribute__((ext_vector_type(4))) float f32x4;

__device__ __forceinline__ unsigned short f2bf(float f) {
  union { float f; unsigned u; } v; v.f = f;
  unsigned u = v.u;
  return (unsigned short)((u + 0x7FFFu + ((u >> 16) & 1u)) >> 16);
}

// Pre-swizzle W1 (fp32 [512,256] row-major) into bf16 MFMA fragment order:
// w1s[((k>>3)*HID + c)*8 + (k&7)]. K-chunk c (32 k's) is the contiguous
// 16 KB at byte offset c*16384 — a linear global_load_lds copy.
__global__ void w1_swz_kernel(const float* __restrict__ W1,
                              unsigned short* __restrict__ w1s) {
  int tid = blockIdx.x * blockDim.x + threadIdx.x;
  if (tid >= DIM * HID) return;
  int k = tid / HID;
  int c = tid - k * HID;
  w1s[(((k >> 3) * HID) + c) * 8 + (k & 7)] = f2bf(W1[tid]);
}

__device__ __forceinline__ short8 cvt8(const f32x4 p0, const f32x4 p1) {
  short8 r;
  r[0] = (short)f2bf(p0[0]); r[1] = (short)f2bf(p0[1]);
  r[2] = (short)f2bf(p0[2]); r[3] = (short)f2bf(p0[3]);
  r[4] = (short)f2bf(p1[0]); r[5] = (short)f2bf(p1[1]);
  r[6] = (short)f2bf(p1[2]); r[7] = (short)f2bf(p1[3]);
  return r;
}

// 4 waves per block, 32 rows: wave w -> src = w&1 (z1/z2), row-tile = w>>1.
// Small LDS (33 KB) + tight regs so ~4 independent blocks co-reside per CU;
// cross-block TLP hides each block's per-chunk barrier drain.
__global__ __launch_bounds__(256, 4) void fa_main_kernel(
    const float* __restrict__ z1, const float* __restrict__ z2,
    const unsigned short* __restrict__ w1s,
    const float* __restrict__ b1, const float* __restrict__ W2,
    const float* __restrict__ b2, float* __restrict__ out, int n) {
  __shared__ unsigned short Bs[2][CB / 2];
  __shared__ float xs[2][ROWS_PB];

  const int t = threadIdx.x;
  const int w = t >> 6;
  const int l = t & 63;
  const int l15 = l & 15, l16 = l >> 4;
  const int src = w & 1;
  const int tile = w >> 1;
  const int row0 = blockIdx.x * ROWS_PB;
  if (row0 >= n) return;
  const int myrow = row0 + tile * 16 + l15;
  const bool rok = myrow < n;
  const float* zz = src ? z2 : z1;
  const float* ap = zz + (size_t)myrow * DIM + (l16 << 3);
  const f32x4 zf4 = (f32x4){0.f, 0.f, 0.f, 0.f};

  // Prologue: stage chunk 0 (async) + A-prefetch chunk 0.
  {
    const char* gsrc = (const char*)w1s + l * 16;
#pragma unroll
    for (int r = w; r < 16; r += 4)
      __builtin_amdgcn_global_load_lds(
          (const __attribute__((address_space(1))) void*)(gsrc + r * 1024),
          (__attribute__((address_space(3))) void*)((char*)&Bs[0][0] + r * 1024),
          16, 0, 0);
  }
  f32x4 pa0 = rok ? *(const f32x4*)(ap) : zf4;
  f32x4 pa1 = rok ? *(const f32x4*)(ap + 4) : zf4;

  f32x4 acc[16];
#pragma unroll
  for (int f = 0; f < 16; ++f) acc[f] = zf4;

  __syncthreads();

  for (int c = 0; c < NCHUNK; ++c) {
    const int cur = c & 1;
    f32x4 na0 = zf4, na1 = zf4;
    if (c + 1 < NCHUNK) {
      // Issue next chunk's B-stage + A-prefetch before this chunk's MFMAs.
      const char* gsrc = (const char*)w1s + (c + 1) * CB + l * 16;
#pragma unroll
      for (int r = w; r < 16; r += 4)
        __builtin_amdgcn_global_load_lds(
            (const __attribute__((address_space(1))) void*)(gsrc + r * 1024),
            (__attribute__((address_space(3))) void*)((char*)&Bs[cur ^ 1][0] +
                                                      r * 1024),
            16, 0, 0);
      const float* apn = ap + ((c + 1) << 5);
      na0 = rok ? *(const f32x4*)(apn) : zf4;
      na1 = rok ? *(const f32x4*)(apn + 4) : zf4;
    }
    const short8 af = cvt8(pa0, pa1);
    const short8* bp = (const short8*)&Bs[cur][0] + (l16 << 8) + l15;
#pragma unroll
    for (int f = 0; f < 16; ++f) {
      const short8 bf = bp[f << 4];
      acc[f] = __builtin_amdgcn_mfma_f32_16x16x32_bf16(af, bf, acc[f], 0, 0, 0);
    }
    pa0 = na0;
    pa1 = na1;
    __syncthreads();  // drains next-chunk stage + A; swaps buffers
  }

  // Per-row logit: x = sum_c relu(H+b1)*W2 (+b2 cancels in the pair diff).
  // C/D layout: hidden col = l15 + 16f, row-in-tile = l16*4 + r.
  float part[4] = {0.f, 0.f, 0.f, 0.f};
#pragma unroll
  for (int f = 0; f < 16; ++f) {
    const int cc = (f << 4) + l15;
    const float w2v = W2[cc];
    const float b1v = b1[cc];
#pragma unroll
    for (int r = 0; r < 4; ++r) {
      const float h = acc[f][r] + b1v;
      part[r] += (h > 0.f) ? h * w2v : 0.f;
    }
  }
#pragma unroll
  for (int r = 0; r < 4; ++r) {
#pragma unroll
    for (int m = 1; m < 16; m <<= 1) part[r] += __shfl_xor(part[r], m, 16);
  }
  if (l15 == 0) {
#pragma unroll
    for (int r = 0; r < 4; ++r)
      xs[src][tile * 16 + (l16 << 2) + r] = part[r];
  }
  __syncthreads();

  // Epilogue: wave w covers rows tile*16..+16, column half (w&1)*256..+256.
  const int colh = src << 8;
#pragma unroll 1
  for (int r = 0; r < 16; ++r) {
    const int rl = tile * 16 + r;
    const int grow = row0 + rl;
    if (grow < n) {
      const float d = xs[1][rl] - xs[0][rl];  // y - x
      const float sx = 1.f / (1.f + __expf(d));
      const float sy = 1.f - sx;
      const size_t off = (size_t)grow * DIM + colh + (l << 2);
      const f32x4 a4 = *(const f32x4*)(z1 + off);
      const f32x4 b4 = *(const f32x4*)(z2 + off);
      f32x4 o;
      o[0] = sx * a4[0] + sy * b4[0];
      o[1] = sx * a4[1] + sy * b4[1];
      o[2] = sx * a4[2] + sy * b4[2];
      o[3] = sx * a4[3] + sy * b4[3];
      *(f32x4*)(out + off) = o;
    }
  }
}

extern "C" void kernel_launch(void* const* d_in, const int* in_sizes, int n_in,
                              void* d_out, int out_size, void* d_ws,
                              size_t ws_size, hipStream_t stream) {
  const float* z1 = (const float*)d_in[0];
  const float* z2 = (const float*)d_in[1];
  const float* W1 = (const float*)d_in[2];
  const float* b1 = (const float*)d_in[3];
  const float* W2 = (const float*)d_in[4];
  const float* b2 = (const float*)d_in[5];
  float* out = (float*)d_out;
  const int n = in_sizes[0] / DIM;
  unsigned short* w1s = (unsigned short*)d_ws;  // 512*256*2 = 256 KB

  hipLaunchKernelGGL(w1_swz_kernel, dim3((DIM * HID + 255) / 256), dim3(256),
                     0, stream, W1, w1s);
  const int nwg = (n + ROWS_PB - 1) / ROWS_PB;
  hipLaunchKernelGGL(fa_main_kernel, dim3(nwg), dim3(256), 0, stream, z1, z2,
                     w1s, b1, W2, b2, out, n);
}